// Round 12
// baseline (107.063 us; speedup 1.0000x reference)
//
#include <hip/hip_runtime.h>
#include <stdint.h>

typedef __attribute__((ext_vector_type(8))) __bf16 bf16x8;
typedef __attribute__((ext_vector_type(4))) float f32x4;

__device__ __forceinline__ unsigned short f2bf(float f) {
  union { float f; unsigned int u; } v; v.f = f;
  unsigned int u = v.u;
  return (unsigned short)((u + 0x7fffu + ((u >> 16) & 1u)) >> 16);
}

__device__ __forceinline__ void async_copy16(const void* g, void* s) {
  __builtin_amdgcn_global_load_lds(
      (__attribute__((address_space(1))) void*)const_cast<void*>(g),
      (__attribute__((address_space(3))) void*)s,
      16, 0, 0);
}

#define HAAR(a, bb, cc, dd, oA, oH, oV, oD)                                    \
  oA = 0.5f * ((a + bb) + (cc + dd));                                          \
  oH = 0.5f * ((a + bb) - (cc + dd));                                          \
  oV = 0.5f * ((a - bb) + (cc - dd));                                          \
  oD = 0.5f * ((a - bb) - (cc - dd));

// ---------------- W fp32 -> bf16 (already [N=768][K=768] row-major) --------
__global__ __launch_bounds__(256) void convw_kernel(const float* __restrict__ W,
                                                    unsigned short* __restrict__ Wb) {
  int i = blockIdx.x * 256 + threadIdx.x;  // 147456 threads x 4 floats
  float4 v = ((const float4*)W)[i];
  uint2 o;
  o.x = (unsigned int)f2bf(v.x) | ((unsigned int)f2bf(v.y) << 16);
  o.y = (unsigned int)f2bf(v.z) | ((unsigned int)f2bf(v.w) << 16);
  ((uint2*)Wb)[i] = o;
}

// ------- 2-level Haar DWT -> bf16 A[M=25088][K=768] in patch layout --------
__global__ __launch_bounds__(256) void dwt2_kernel(const float* __restrict__ x,
                                                   unsigned short* __restrict__ A) {
  int tid = blockIdx.x * 256 + threadIdx.x;  // 128*3*56*56 = 1204224
  int J = tid % 56;
  int t = tid / 56;
  int I = t % 56;
  t /= 56;  // t = b*3 + c
  int c = t % 3;
  int b = t / 3;

  const float* xp = x + (((size_t)t * 224 + 4 * I) * 224 + 4 * J);
  float4 r0 = *(const float4*)(xp);
  float4 r1 = *(const float4*)(xp + 224);
  float4 r2 = *(const float4*)(xp + 448);
  float4 r3 = *(const float4*)(xp + 672);

  float A1[2][2], H1[2][2], V1[2][2], D1[2][2];
  HAAR(r0.x, r0.y, r1.x, r1.y, A1[0][0], H1[0][0], V1[0][0], D1[0][0]);
  HAAR(r0.z, r0.w, r1.z, r1.w, A1[0][1], H1[0][1], V1[0][1], D1[0][1]);
  HAAR(r2.x, r2.y, r3.x, r3.y, A1[1][0], H1[1][0], V1[1][0], D1[1][0]);
  HAAR(r2.z, r2.w, r3.z, r3.w, A1[1][1], H1[1][1], V1[1][1], D1[1][1]);

  auto aidx = [&](int y, int xx) -> size_t {
    int mrow = b * 196 + (y >> 4) * 14 + (xx >> 4);
    int k = c * 256 + (y & 15) * 16 + (xx & 15);
    return (size_t)mrow * 768 + (size_t)k;
  };
  auto store2 = [&](int y, int xx, float v0, float v1) {
    unsigned int p = (unsigned int)f2bf(v0) | ((unsigned int)f2bf(v1) << 16);
    *(unsigned int*)(A + aidx(y, xx)) = p;  // xx even -> 4B aligned, same patch
  };

  int y0 = 2 * I, x0 = 2 * J;
  store2(y0,           112 + x0, H1[0][0], H1[0][1]);
  store2(y0 + 1,       112 + x0, H1[1][0], H1[1][1]);
  store2(112 + y0,     x0,       V1[0][0], V1[0][1]);
  store2(112 + y0 + 1, x0,       V1[1][0], V1[1][1]);
  store2(112 + y0,     112 + x0, D1[0][0], D1[0][1]);
  store2(112 + y0 + 1, 112 + x0, D1[1][0], D1[1][1]);

  float vA2, vH2, vV2, vD2;
  HAAR(A1[0][0], A1[0][1], A1[1][0], A1[1][1], vA2, vH2, vV2, vD2);
  A[aidx(I,      J)]      = f2bf(vA2);
  A[aidx(I,      56 + J)] = f2bf(vH2);
  A[aidx(56 + I, J)]      = f2bf(vV2);
  A[aidx(56 + I, 56 + J)] = f2bf(vD2);
}

// --------- bf16 MFMA GEMM: C[M][N] = A[M][K] * Bt[N][K]^T + bias -----------
// M=25088, N=768, K=768. 128x192 block, BK=32, 4 waves of 64x96 each.
// r3-EXACT schedule: per iter {vmcnt(5) -> s_barrier -> stage(kt+2) ->
// ds_reads -> MFMA -> lgkmcnt(0)}. Stage sits AFTER the barrier so buffer
// overwrite is fenced (r11's pre-barrier stage raced laggard readers).
// Triple buffer, prefetch-2, proven chunk-XOR swizzle. 784 = 8 XCDs x 98.
// Template<WRITE_C>: false variant sinks acc via asm (epilogue ablation).
template <bool WRITE_C>
__global__ __launch_bounds__(256) void gemm_kernel(const unsigned short* __restrict__ A,
                                                   const unsigned short* __restrict__ Bt,
                                                   const float* __restrict__ bias,
                                                   float* __restrict__ C) {
  constexpr int K = 768, N = 768;
  constexpr int NT = 24;  // K / 32
  __shared__ unsigned short As[3][128 * 32];  // 8 KB per buffer
  __shared__ unsigned short Bs[3][192 * 32];  // 12 KB per buffer

  // XCD swizzle: 784 = 8 XCDs x 98 consecutive tiles (bijective).
  const int orig = blockIdx.x;
  const int tile = (orig & 7) * 98 + (orig >> 3);
  const int bm = tile >> 2, bn = tile & 3;  // bn fastest: same-bm neighbors
  const int mbase = bm * 128, nbase = bn * 192;

  const int tid = threadIdx.x;
  const int lane = tid & 63;
  const int wave = tid >> 6;
  const int wr = wave >> 1, wc = wave & 1;  // wave tile 64x96 at (wr*64, wc*96)

  f32x4 acc[4][6] = {};

  // --- staging: A 2 insts/wave, B 3 insts/wave; dest linear per inst ---
  // dest row (inst i) = i*64 + wave*16 + (lane>>2), phys chunk = lane&3.
  // source chunk pre-swizzled: kcs = (lane&3) ^ ((lane>>3)&3)
  // (P(row) = (row>>1)&3; inst/wave terms vanish mod 4 — involution
  // matches read-side chq).
  const int srow = wave * 16 + (lane >> 2);
  const int kcs = (lane & 3) ^ ((lane >> 3) & 3);
  const unsigned short* gA[2];
  const unsigned short* gB[3];
#pragma unroll
  for (int i = 0; i < 2; ++i) gA[i] = A + (size_t)(mbase + i * 64 + srow) * K + kcs * 8;
#pragma unroll
  for (int j = 0; j < 3; ++j) gB[j] = Bt + (size_t)(nbase + j * 64 + srow) * K + kcs * 8;

  auto stage = [&](int buf, int kt) {
    char* sa = (char*)As + buf * 8192 + wave * 1024;
    char* sb = (char*)Bs + buf * 12288 + wave * 1024;
    const int ko = kt * 32;
    async_copy16(gA[0] + ko, sa);
    async_copy16(gA[1] + ko, sa + 4096);
    async_copy16(gB[0] + ko, sb);
    async_copy16(gB[1] + ko, sb + 4096);
    async_copy16(gB[2] + ko, sb + 8192);
  };

  // fragment geometry (r3-proven conflict-free)
  const int fr = lane & 15;
  const int kq = lane >> 4;
  const int chq = kq ^ ((fr >> 1) & 3);

  stage(0, 0);
  stage(1, 1);

#pragma unroll
  for (int kt = 0; kt < NT; ++kt) {
    // counted wait FIRST (own tile-kt loads landed; kt+1 stays in flight),
    if (kt < NT - 1)
      asm volatile("s_waitcnt vmcnt(5)" ::: "memory");
    else
      asm volatile("s_waitcnt vmcnt(0)" ::: "memory");
    // then barrier (all waves' loads landed + prev reads lgkm-fenced),
    __builtin_amdgcn_s_barrier();
    // then stage (overwrites buf[(kt-1)%3], whose readers are behind us).
    if (kt + 2 < NT) stage((kt + 2) % 3, kt + 2);

    const char* pa = (const char*)As + (kt % 3) * 8192 + (wr * 64 + fr) * 64 + chq * 16;
    const char* pb = (const char*)Bs + (kt % 3) * 12288 + (wc * 96 + fr) * 64 + chq * 16;
    bf16x8 af[4], bv[6];
#pragma unroll
    for (int mi = 0; mi < 4; ++mi) af[mi] = *(const bf16x8*)(pa + mi * 1024);
#pragma unroll
    for (int ni = 0; ni < 6; ++ni) bv[ni] = *(const bf16x8*)(pb + ni * 1024);
#pragma unroll
    for (int mi = 0; mi < 4; ++mi)
#pragma unroll
      for (int ni = 0; ni < 6; ++ni)
        acc[mi][ni] = __builtin_amdgcn_mfma_f32_16x16x32_bf16(af[mi], bv[ni],
                                                              acc[mi][ni], 0, 0, 0);
    asm volatile("s_waitcnt lgkmcnt(0)" ::: "memory");  // reads done pre-barrier
  }

  if (WRITE_C) {
    // epilogue: C col = lane&15, row = (lane>>4)*4 + j ; fuse bias
    const int rq = lane >> 4;
#pragma unroll
    for (int ni = 0; ni < 6; ++ni) {
      int n = nbase + wc * 96 + ni * 16 + fr;
      float bb = bias[n];
#pragma unroll
      for (int mi = 0; mi < 4; ++mi) {
        int mrow = mbase + wr * 64 + mi * 16 + rq * 4;
        f32x4 v = acc[mi][ni];
#pragma unroll
        for (int j = 0; j < 4; ++j) C[(size_t)(mrow + j) * N + n] = v[j] + bb;
      }
    }
  } else {
    // ablation: keep every accumulator live without memory traffic
#pragma unroll
    for (int mi = 0; mi < 4; ++mi)
#pragma unroll
      for (int ni = 0; ni < 6; ++ni)
        asm volatile("" ::"v"(acc[mi][ni][0]), "v"(acc[mi][ni][1]),
                     "v"(acc[mi][ni][2]), "v"(acc[mi][ni][3]));
  }
}

extern "C" void kernel_launch(void* const* d_in, const int* in_sizes, int n_in,
                              void* d_out, int out_size, void* d_ws, size_t ws_size,
                              hipStream_t stream) {
  const float* x = (const float*)d_in[0];     // (128,3,224,224) f32
  const float* W = (const float*)d_in[1];     // (768,3,16,16)  f32
  const float* bias = (const float*)d_in[2];  // (768,)         f32
  float* out = (float*)d_out;                 // (128,196,768)  f32

  unsigned short* A = (unsigned short*)d_ws;                        // 25088*768 bf16
  unsigned short* Wb = (unsigned short*)((char*)d_ws + 38535168);   // 589824 bf16

  convw_kernel<<<576, 256, 0, stream>>>(W, Wb);
  dwt2_kernel<<<4704, 256, 0, stream>>>(x, A);
  gemm_kernel<false><<<784, 256, 0, stream>>>(A, Wb, bias, out);  // ablation (no stores)
  gemm_kernel<true><<<784, 256, 0, stream>>>(A, Wb, bias, out);   // real
}

// Round 13
// 68.837 us; speedup vs baseline: 1.5553x; 1.5553x over previous
//
#include <hip/hip_runtime.h>
#include <stdint.h>

typedef __attribute__((ext_vector_type(8))) __bf16 bf16x8;
typedef __attribute__((ext_vector_type(4))) float f32x4;

__device__ __forceinline__ unsigned short f2bf(float f) {
  union { float f; unsigned int u; } v; v.f = f;
  unsigned int u = v.u;
  return (unsigned short)((u + 0x7fffu + ((u >> 16) & 1u)) >> 16);
}

__device__ __forceinline__ void async_copy16(const void* g, void* s) {
  __builtin_amdgcn_global_load_lds(
      (__attribute__((address_space(1))) void*)const_cast<void*>(g),
      (__attribute__((address_space(3))) void*)s,
      16, 0, 0);
}

#define HAAR(a, bb, cc, dd, oA, oH, oV, oD)                                    \
  oA = 0.5f * ((a + bb) + (cc + dd));                                          \
  oH = 0.5f * ((a + bb) - (cc + dd));                                          \
  oV = 0.5f * ((a - bb) + (cc - dd));                                          \
  oD = 0.5f * ((a - bb) - (cc - dd));

// ---------------- W fp32 -> bf16 (already [N=768][K=768] row-major) --------
__global__ __launch_bounds__(256) void convw_kernel(const float* __restrict__ W,
                                                    unsigned short* __restrict__ Wb) {
  int i = blockIdx.x * 256 + threadIdx.x;  // 147456 threads x 4 floats
  float4 v = ((const float4*)W)[i];
  uint2 o;
  o.x = (unsigned int)f2bf(v.x) | ((unsigned int)f2bf(v.y) << 16);
  o.y = (unsigned int)f2bf(v.z) | ((unsigned int)f2bf(v.w) << 16);
  ((uint2*)Wb)[i] = o;
}

// ------- 2-level Haar DWT -> bf16 A[M=25088][K=768] in patch layout --------
__global__ __launch_bounds__(256) void dwt2_kernel(const float* __restrict__ x,
                                                   unsigned short* __restrict__ A) {
  int tid = blockIdx.x * 256 + threadIdx.x;  // 128*3*56*56 = 1204224
  int J = tid % 56;
  int t = tid / 56;
  int I = t % 56;
  t /= 56;  // t = b*3 + c
  int c = t % 3;
  int b = t / 3;

  const float* xp = x + (((size_t)t * 224 + 4 * I) * 224 + 4 * J);
  float4 r0 = *(const float4*)(xp);
  float4 r1 = *(const float4*)(xp + 224);
  float4 r2 = *(const float4*)(xp + 448);
  float4 r3 = *(const float4*)(xp + 672);

  float A1[2][2], H1[2][2], V1[2][2], D1[2][2];
  HAAR(r0.x, r0.y, r1.x, r1.y, A1[0][0], H1[0][0], V1[0][0], D1[0][0]);
  HAAR(r0.z, r0.w, r1.z, r1.w, A1[0][1], H1[0][1], V1[0][1], D1[0][1]);
  HAAR(r2.x, r2.y, r3.x, r3.y, A1[1][0], H1[1][0], V1[1][0], D1[1][0]);
  HAAR(r2.z, r2.w, r3.z, r3.w, A1[1][1], H1[1][1], V1[1][1], D1[1][1]);

  auto aidx = [&](int y, int xx) -> size_t {
    int mrow = b * 196 + (y >> 4) * 14 + (xx >> 4);
    int k = c * 256 + (y & 15) * 16 + (xx & 15);
    return (size_t)mrow * 768 + (size_t)k;
  };
  auto store2 = [&](int y, int xx, float v0, float v1) {
    unsigned int p = (unsigned int)f2bf(v0) | ((unsigned int)f2bf(v1) << 16);
    *(unsigned int*)(A + aidx(y, xx)) = p;  // xx even -> 4B aligned, same patch
  };

  int y0 = 2 * I, x0 = 2 * J;
  store2(y0,           112 + x0, H1[0][0], H1[0][1]);
  store2(y0 + 1,       112 + x0, H1[1][0], H1[1][1]);
  store2(112 + y0,     x0,       V1[0][0], V1[0][1]);
  store2(112 + y0 + 1, x0,       V1[1][0], V1[1][1]);
  store2(112 + y0,     112 + x0, D1[0][0], D1[0][1]);
  store2(112 + y0 + 1, 112 + x0, D1[1][0], D1[1][1]);

  float vA2, vH2, vV2, vD2;
  HAAR(A1[0][0], A1[0][1], A1[1][0], A1[1][1], vA2, vH2, vV2, vD2);
  A[aidx(I,      J)]      = f2bf(vA2);
  A[aidx(I,      56 + J)] = f2bf(vH2);
  A[aidx(56 + I, J)]      = f2bf(vV2);
  A[aidx(56 + I, 56 + J)] = f2bf(vD2);
}

// --------- bf16 MFMA GEMM: C[M][N] = A[M][K] * Bt[N][K]^T + bias -----------
// M=25088, N=768, K=768. 128x192 block, BK=64 (12 iters: sync overhead
// halved vs BK=32), 4 waves of 64x96. Double-buffer (80 KB -> 2 blocks/CU).
// Per iter: {stageA(t+1) | kh0 reads -> lgkm -> setprio MFMA | stageB(t+1)
// | kh1 reads -> lgkm -> setprio MFMA | vmcnt(0)+barrier}. Stage is issued
// AFTER the barrier fencing prior readers (r12 discipline, race-free).
// Row=128B=8 chunks; XOR swizzle P(row)=row&7 (2 lanes/chunk = free).
__global__ __launch_bounds__(256) void gemm_kernel(const unsigned short* __restrict__ A,
                                                   const unsigned short* __restrict__ Bt,
                                                   const float* __restrict__ bias,
                                                   float* __restrict__ C) {
  constexpr int K = 768, N = 768;
  constexpr int NT = 12;  // K / 64
  __shared__ unsigned short As[2][128 * 64];  // 16 KB per buffer
  __shared__ unsigned short Bs[2][192 * 64];  // 24 KB per buffer

  // XCD swizzle: 784 = 8 XCDs x 98 consecutive tiles (bijective).
  const int orig = blockIdx.x;
  const int tile = (orig & 7) * 98 + (orig >> 3);
  const int bm = tile >> 2, bn = tile & 3;
  const int mbase = bm * 128, nbase = bn * 192;

  const int tid = threadIdx.x;
  const int lane = tid & 63;
  const int wave = tid >> 6;
  const int wr = wave >> 1, wc = wave & 1;  // wave tile 64x96

  f32x4 acc[4][6] = {};

  // --- staging: A 4 instr/wave (16 KB), B 6 instr/wave (24 KB) ---
  // dest (inst i): i*4096 + wave*1024 + lane*16 -> row = i*32+wave*8+(l>>3),
  // phys chunk = l&7. Source logical chunk = phys ^ (row&7):
  // kcs = (l&7) ^ ((l>>3)&7)   (inst/wave terms vanish mod 8).
  const int srow = wave * 8 + (lane >> 3);
  const int kcs = (lane & 7) ^ ((lane >> 3) & 7);
  const unsigned short* gA[4];
  const unsigned short* gB[6];
#pragma unroll
  for (int i = 0; i < 4; ++i) gA[i] = A + (size_t)(mbase + i * 32 + srow) * K + kcs * 8;
#pragma unroll
  for (int j = 0; j < 6; ++j) gB[j] = Bt + (size_t)(nbase + j * 32 + srow) * K + kcs * 8;

  auto stageA = [&](int buf, int kt) {
    char* sa = (char*)As + buf * 16384 + wave * 1024;
    const int ko = kt * 64;
#pragma unroll
    for (int i = 0; i < 4; ++i) async_copy16(gA[i] + ko, sa + i * 4096);
  };
  auto stageB = [&](int buf, int kt) {
    char* sb = (char*)Bs + buf * 24576 + wave * 1024;
    const int ko = kt * 64;
#pragma unroll
    for (int j = 0; j < 6; ++j) async_copy16(gB[j] + ko, sb + j * 4096);
  };

  // fragment geometry: row stride 128B; logical chunk (s*4+kq) ^ (fr&7)
  const int fr = lane & 15;
  const int kq = lane >> 4;
  const int ch0 = ((0 * 4 + kq) ^ (fr & 7)) * 16;  // k-half 0
  const int ch1 = ((1 * 4 + kq) ^ (fr & 7)) * 16;  // k-half 1

  // prologue: stage tile 0, drain, barrier
  stageA(0, 0);
  stageB(0, 0);
  asm volatile("s_waitcnt vmcnt(0)" ::: "memory");
  __builtin_amdgcn_s_barrier();

#pragma unroll
  for (int kt = 0; kt < NT; ++kt) {
    const int cb = kt & 1;
    const char* pa = (const char*)As + cb * 16384 + (wr * 64 + fr) * 128;
    const char* pb = (const char*)Bs + cb * 24576 + (wc * 96 + fr) * 128;
    bf16x8 af[4], bv[6];

    // ---- k-half 0: stage A(t+1) | 10 frag reads | 24 MFMA ----
    if (kt + 1 < NT) stageA(cb ^ 1, kt + 1);
#pragma unroll
    for (int ni = 0; ni < 6; ++ni) bv[ni] = *(const bf16x8*)(pb + ni * 2048 + ch0);
#pragma unroll
    for (int mi = 0; mi < 4; ++mi) af[mi] = *(const bf16x8*)(pa + mi * 2048 + ch0);
    asm volatile("s_waitcnt lgkmcnt(0)" ::: "memory");
    __builtin_amdgcn_sched_barrier(0);
    __builtin_amdgcn_s_setprio(1);
#pragma unroll
    for (int mi = 0; mi < 4; ++mi)
#pragma unroll
      for (int ni = 0; ni < 6; ++ni)
        acc[mi][ni] = __builtin_amdgcn_mfma_f32_16x16x32_bf16(af[mi], bv[ni],
                                                              acc[mi][ni], 0, 0, 0);
    __builtin_amdgcn_s_setprio(0);

    // ---- k-half 1: stage B(t+1) | 10 frag reads | 24 MFMA ----
    if (kt + 1 < NT) stageB(cb ^ 1, kt + 1);
#pragma unroll
    for (int ni = 0; ni < 6; ++ni) bv[ni] = *(const bf16x8*)(pb + ni * 2048 + ch1);
#pragma unroll
    for (int mi = 0; mi < 4; ++mi) af[mi] = *(const bf16x8*)(pa + mi * 2048 + ch1);
    asm volatile("s_waitcnt lgkmcnt(0)" ::: "memory");
    __builtin_amdgcn_sched_barrier(0);
    __builtin_amdgcn_s_setprio(1);
#pragma unroll
    for (int mi = 0; mi < 4; ++mi)
#pragma unroll
      for (int ni = 0; ni < 6; ++ni)
        acc[mi][ni] = __builtin_amdgcn_mfma_f32_16x16x32_bf16(af[mi], bv[ni],
                                                              acc[mi][ni], 0, 0, 0);
    __builtin_amdgcn_s_setprio(0);

    // ---- iter end: tile t+1 landed (had whole iter to fly), reads fenced ----
    if (kt + 1 < NT) {
      asm volatile("s_waitcnt vmcnt(0)" ::: "memory");
      __builtin_amdgcn_s_barrier();  // all waves: loads visible, reads done
    }
  }

  // epilogue: C col = lane&15, row = (lane>>4)*4 + j ; fuse bias
  const int rq = lane >> 4;
#pragma unroll
  for (int ni = 0; ni < 6; ++ni) {
    int n = nbase + wc * 96 + ni * 16 + fr;
    float bb = bias[n];
#pragma unroll
    for (int mi = 0; mi < 4; ++mi) {
      int mrow = mbase + wr * 64 + mi * 16 + rq * 4;
      f32x4 v = acc[mi][ni];
#pragma unroll
      for (int j = 0; j < 4; ++j) C[(size_t)(mrow + j) * N + n] = v[j] + bb;
    }
  }
}

extern "C" void kernel_launch(void* const* d_in, const int* in_sizes, int n_in,
                              void* d_out, int out_size, void* d_ws, size_t ws_size,
                              hipStream_t stream) {
  const float* x = (const float*)d_in[0];     // (128,3,224,224) f32
  const float* W = (const float*)d_in[1];     // (768,3,16,16)  f32
  const float* bias = (const float*)d_in[2];  // (768,)         f32
  float* out = (float*)d_out;                 // (128,196,768)  f32

  unsigned short* A = (unsigned short*)d_ws;                        // 25088*768 bf16
  unsigned short* Wb = (unsigned short*)((char*)d_ws + 38535168);   // 589824 bf16

  convw_kernel<<<576, 256, 0, stream>>>(W, Wb);
  dwt2_kernel<<<4704, 256, 0, stream>>>(x, A);
  gemm_kernel<<<784, 256, 0, stream>>>(A, Wb, bias, out);
}